// Round 5
// baseline (1247.224 us; speedup 1.0000x reference)
//
#include <hip/hip_runtime.h>

typedef __attribute__((ext_vector_type(8))) __bf16 bf16x8;
typedef __attribute__((ext_vector_type(16))) float f32x16;

#define GLOAD_LDS16(g, l)                                                     \
  __builtin_amdgcn_global_load_lds(                                           \
      (const __attribute__((address_space(1))) void*)(g),                     \
      (__attribute__((address_space(3))) void*)(l), 16, 0, 0)

#define BAR() __builtin_amdgcn_s_barrier()
#define SB0() __builtin_amdgcn_sched_barrier(0)
#define LGKM(n)                                                               \
  do {                                                                        \
    asm volatile("s_waitcnt lgkmcnt(" #n ")" ::: "memory");                   \
    SB0();                                                                    \
  } while (0)
#define VMCNT0() asm volatile("s_waitcnt vmcnt(0)" ::: "memory")
#define PRIO1() __builtin_amdgcn_s_setprio(1)
#define PRIO0() __builtin_amdgcn_s_setprio(0)
#define MFMA32 __builtin_amdgcn_mfma_f32_32x32x16_bf16

__device__ __forceinline__ unsigned short f32_to_bf16(float f) {
  unsigned int u = __builtin_bit_cast(unsigned int, f);
  u += 0x7FFFu + ((u >> 16) & 1u);
  return (unsigned short)(u >> 16);
}

// ---------------- f32 -> bf16 conversion ----------------------------------
__global__ void conv_f32_bf16(const float* __restrict__ in,
                              unsigned short* __restrict__ out, int n4) {
  int stride = gridDim.x * blockDim.x;
  for (int i = blockIdx.x * blockDim.x + threadIdx.x; i < n4; i += stride) {
    float4 v = reinterpret_cast<const float4*>(in)[i];
    ushort4 o;
    o.x = f32_to_bf16(v.x);
    o.y = f32_to_bf16(v.y);
    o.z = f32_to_bf16(v.z);
    o.w = f32_to_bf16(v.w);
    reinterpret_cast<ushort4*>(out)[i] = o;
  }
}

// ---------------- FWHT rows of 8192, * 1/sqrt(8192), bf16 out --------------
__global__ void fwht_rows_bf16(const float* __restrict__ in,
                               unsigned short* __restrict__ out) {
  __shared__ float s[8192];
  const int tid = threadIdx.x;  // 256 threads
  const float* row = in + (size_t)blockIdx.x * 8192;
#pragma unroll
  for (int i = 0; i < 8; ++i)
    reinterpret_cast<float4*>(s)[tid + i * 256] =
        reinterpret_cast<const float4*>(row)[tid + i * 256];
  for (int h = 1; h < 8192; h <<= 1) {
    __syncthreads();
#pragma unroll
    for (int it = 0; it < 16; ++it) {
      int i = tid + it * 256;
      int j = ((i & ~(h - 1)) << 1) | (i & (h - 1));
      float a = s[j], b = s[j + h];
      s[j] = a + b;
      s[j + h] = a - b;
    }
  }
  __syncthreads();
  const float scale = 0.011048543456039806f;  // 1/sqrt(8192)
  unsigned short* orow = out + (size_t)blockIdx.x * 8192;
#pragma unroll
  for (int i = 0; i < 8; ++i) {
    float4 v = reinterpret_cast<const float4*>(s)[tid + i * 256];
    ushort4 o;
    o.x = f32_to_bf16(v.x * scale);
    o.y = f32_to_bf16(v.y * scale);
    o.z = f32_to_bf16(v.z * scale);
    o.w = f32_to_bf16(v.w * scale);
    reinterpret_cast<ushort4*>(orow)[tid + i * 256] = o;
  }
}

// ======================= GEMM2: C(f32) = A · Bt^T ==========================
// tile 256x256, BK=64, 8 waves (2M x 4N), per-wave 128x64 as 4x2 of 32x32.
// 1 barrier + 1 vmcnt(0) per K-tile; all 24 frag reads at tile head,
// counted lgkm(8) gates group1 (m-tiles 0,1), lgkm(0) gates group2 (2,3).
// LDS bytes: A[2][32768] @0 ; B[2][32768] @65536.
#define G2T(BI, tt)                                                           \
  {                                                                           \
    _Pragma("unroll") for (int mi = 0; mi < 2; ++mi)                          \
        _Pragma("unroll") for (int ks = 0; ks < 4; ++ks) ra[mi][ks] =         \
            *(const bf16x8*)(Lb + (BI)*32768 + aB + mi * 4096 + sk[ks]);      \
    _Pragma("unroll") for (int ni = 0; ni < 2; ++ni)                          \
        _Pragma("unroll") for (int ks = 0; ks < 4; ++ks) rb[ni][ks] =         \
            *(const bf16x8*)(Lb + 65536 + (BI)*32768 + bB + ni * 4096 +       \
                             sk[ks]);                                         \
    _Pragma("unroll") for (int mi = 0; mi < 2; ++mi)                          \
        _Pragma("unroll") for (int ks = 0; ks < 4; ++ks) ra2[mi][ks] =        \
            *(const bf16x8*)(Lb + (BI)*32768 + aB + 8192 + mi * 4096 +        \
                             sk[ks]);                                         \
    SB0();                                                                    \
    if ((tt) + 1 < NT) {                                                      \
      unsigned short* dA = L + (((BI) ^ 1) * 16384) + wid * 512;              \
      unsigned short* dB = L + 32768 + (((BI) ^ 1) * 16384) + wid * 512;      \
      _Pragma("unroll") for (int i = 0; i < 4; ++i) {                         \
        GLOAD_LDS16(pA + i * s64, dA + i * 4096);                             \
        GLOAD_LDS16(pB + i * s64, dB + i * 4096);                             \
      }                                                                       \
    }                                                                         \
    SB0();                                                                    \
    LGKM(8);                                                                  \
    PRIO1();                                                                  \
    _Pragma("unroll") for (int ks = 0; ks < 4; ++ks)                          \
        _Pragma("unroll") for (int mi = 0; mi < 2; ++mi)                      \
            _Pragma("unroll") for (int ni = 0; ni < 2; ++ni) acc[mi][ni] =    \
                MFMA32(ra[mi][ks], rb[ni][ks], acc[mi][ni], 0, 0, 0);         \
    PRIO0();                                                                  \
    SB0();                                                                    \
    LGKM(0);                                                                  \
    PRIO1();                                                                  \
    _Pragma("unroll") for (int ks = 0; ks < 4; ++ks)                          \
        _Pragma("unroll") for (int mi = 0; mi < 2; ++mi)                      \
            _Pragma("unroll") for (int ni = 0; ni < 2; ++ni)                  \
                acc[2 + mi][ni] =                                             \
                    MFMA32(ra2[mi][ks], rb[ni][ks], acc[2 + mi][ni], 0, 0, 0);\
    PRIO0();                                                                  \
    VMCNT0();                                                                 \
    BAR();                                                                    \
    pA += 128;                                                                \
    pB += 128;                                                                \
  }

__launch_bounds__(512, 2)
__global__ void gemm2_32(const unsigned short* __restrict__ A,
                         const unsigned short* __restrict__ Bt,
                         float* __restrict__ C, int M, int N, int K) {
  __shared__ __align__(16) unsigned short L[65536];
  const int tid = threadIdx.x, lane = tid & 63, wid = tid >> 6;
  const int wr = wid >> 2, wc = wid & 3;
  const int nbx = N >> 8;
  const int cpx = (int)gridDim.x >> 3;
  const int swz = ((int)blockIdx.x & 7) * cpx + ((int)blockIdx.x >> 3);
  const int bm = (swz / nbx) << 8, bn = (swz % nbx) << 8;
  const int NT = K >> 6;

  // 32x32x16 fragment addressing: row = lane&31, k = (lane>>5)*8 + e.
  const int rl = lane & 31, kk = lane >> 5, rx = rl & 7;
  int sk[4];
#pragma unroll
  for (int ks = 0; ks < 4; ++ks) sk[ks] = ((((ks << 1) | kk) ^ rx) << 4);
  const int aB = wr * 16384 + rl * 128;  // bytes into A-buf (256 rows x 128B)
  const int bB = wc * 8192 + rl * 128;   // bytes into B-buf

  // stage source (inverse swizzle folded into global col)
  const int swzc = ((lane & 7) ^ (lane >> 3)) << 4;
  const char* pA = (const char*)A +
                   ((size_t)(bm + (wid << 3) + (lane >> 3)) * K) * 2 + swzc;
  const char* pB = (const char*)Bt +
                   ((size_t)(bn + (wid << 3) + (lane >> 3)) * K) * 2 + swzc;
  const size_t s64 = (size_t)K * 128;  // 64 rows stride (bytes)
  const char* Lb = (const char*)L;

  {  // prologue: stage tile 0 -> buf0
    unsigned short* dA = L + wid * 512;
    unsigned short* dB = L + 32768 + wid * 512;
#pragma unroll
    for (int i = 0; i < 4; ++i) {
      GLOAD_LDS16(pA + i * s64, dA + i * 4096);
      GLOAD_LDS16(pB + i * s64, dB + i * 4096);
    }
  }
  pA += 128;
  pB += 128;

  f32x16 acc[4][2];
#pragma unroll
  for (int m = 0; m < 4; ++m)
#pragma unroll
    for (int n = 0; n < 2; ++n) acc[m][n] = (f32x16)0.0f;
  bf16x8 ra[2][4], rb[2][4], ra2[2][4];

  VMCNT0();
  BAR();

  for (int t = 0; t < NT; t += 2) {
    G2T(0, t)
    G2T(1, t + 1)
  }

  // epilogue: C/D map: col = lane&31, row = (e&3) + 8*(e>>2) + 4*(lane>>5)
#pragma unroll
  for (int mi = 0; mi < 4; ++mi)
#pragma unroll
    for (int ni = 0; ni < 2; ++ni)
#pragma unroll
      for (int e = 0; e < 16; ++e) {
        size_t row = (size_t)(bm + wr * 128 + mi * 32 + (e & 3) +
                              ((e >> 2) << 3) + (kk << 2));
        size_t col = (size_t)(bn + wc * 64 + ni * 32 + rl);
        C[row * N + col] = acc[mi][ni][e];
      }
}

// ======================= GEMM1: dual-B + silu fuse =========================
// tile 256x128, BK=64, 8 waves (4M x 2N), per-wave 64x64 dual as 2x2 of 32x32.
// LDS bytes: A[2][32768] @0 ; B1[2][16384] @65536 ; B3[2][16384] @98304.
#define G1T(BI, tt)                                                           \
  {                                                                           \
    _Pragma("unroll") for (int mi = 0; mi < 2; ++mi)                          \
        _Pragma("unroll") for (int ks = 0; ks < 4; ++ks) ra[mi][ks] =         \
            *(const bf16x8*)(Lb + (BI)*32768 + aB + mi * 4096 + sk[ks]);      \
    _Pragma("unroll") for (int ni = 0; ni < 2; ++ni)                          \
        _Pragma("unroll") for (int ks = 0; ks < 4; ++ks) rb1[ni][ks] =        \
            *(const bf16x8*)(Lb + 65536 + (BI)*16384 + bB + ni * 4096 +       \
                             sk[ks]);                                         \
    _Pragma("unroll") for (int ni = 0; ni < 2; ++ni)                          \
        _Pragma("unroll") for (int ks = 0; ks < 4; ++ks) rb3[ni][ks] =        \
            *(const bf16x8*)(Lb + 98304 + (BI)*16384 + bB + ni * 4096 +       \
                             sk[ks]);                                         \
    SB0();                                                                    \
    if ((tt) + 1 < NT) {                                                      \
      unsigned short* dA = L + (((BI) ^ 1) * 16384) + wid * 512;              \
      unsigned short* dB1 = L + 32768 + (((BI) ^ 1) * 8192) + wid * 512;      \
      unsigned short* dB3 = L + 49152 + (((BI) ^ 1) * 8192) + wid * 512;      \
      _Pragma("unroll") for (int i = 0; i < 4; ++i)                           \
          GLOAD_LDS16(pA + i * s64, dA + i * 4096);                           \
      _Pragma("unroll") for (int i = 0; i < 2; ++i) {                         \
        GLOAD_LDS16(pB1 + i * s64, dB1 + i * 4096);                           \
        GLOAD_LDS16(pB3 + i * s64, dB3 + i * 4096);                           \
      }                                                                       \
    }                                                                         \
    SB0();                                                                    \
    LGKM(8);                                                                  \
    PRIO1();                                                                  \
    _Pragma("unroll") for (int ks = 0; ks < 4; ++ks)                          \
        _Pragma("unroll") for (int mi = 0; mi < 2; ++mi)                      \
            _Pragma("unroll") for (int ni = 0; ni < 2; ++ni) accG[mi][ni] =   \
                MFMA32(ra[mi][ks], rb1[ni][ks], accG[mi][ni], 0, 0, 0);       \
    PRIO0();                                                                  \
    SB0();                                                                    \
    LGKM(0);                                                                  \
    PRIO1();                                                                  \
    _Pragma("unroll") for (int ks = 0; ks < 4; ++ks)                          \
        _Pragma("unroll") for (int mi = 0; mi < 2; ++mi)                      \
            _Pragma("unroll") for (int ni = 0; ni < 2; ++ni) accL[mi][ni] =   \
                MFMA32(ra[mi][ks], rb3[ni][ks], accL[mi][ni], 0, 0, 0);       \
    PRIO0();                                                                  \
    VMCNT0();                                                                 \
    BAR();                                                                    \
    pA += 128;                                                                \
    pB1 += 128;                                                               \
    pB3 += 128;                                                               \
  }

__launch_bounds__(512, 2)
__global__ void gemm1_32(const unsigned short* __restrict__ A,
                         const unsigned short* __restrict__ B1p,
                         const unsigned short* __restrict__ B3p,
                         unsigned short* __restrict__ Hout, int M, int N,
                         int K) {
  __shared__ __align__(16) unsigned short L[65536];
  const int tid = threadIdx.x, lane = tid & 63, wid = tid >> 6;
  const int wr = wid >> 1, wc = wid & 1;
  const int nby = M >> 8;  // 32
  const int cpx = (int)gridDim.x >> 3;
  const int swz = ((int)blockIdx.x & 7) * cpx + ((int)blockIdx.x >> 3);
  const int bm = (swz % nby) << 8;  // column-major: chunk shares B panels
  const int bn = (swz / nby) << 7;
  const int NT = K >> 6;

  const int rl = lane & 31, kk = lane >> 5, rx = rl & 7;
  int sk[4];
#pragma unroll
  for (int ks = 0; ks < 4; ++ks) sk[ks] = ((((ks << 1) | kk) ^ rx) << 4);
  const int aB = wr * 8192 + rl * 128;  // bytes into A-buf (wave rows 64)
  const int bB = wc * 8192 + rl * 128;  // bytes into B-buf (wave cols 64)

  const int swzc = ((lane & 7) ^ (lane >> 3)) << 4;
  const char* pA = (const char*)A +
                   ((size_t)(bm + (wid << 3) + (lane >> 3)) * K) * 2 + swzc;
  const char* pB1 = (const char*)B1p +
                    ((size_t)(bn + (wid << 3) + (lane >> 3)) * K) * 2 + swzc;
  const char* pB3 = (const char*)B3p +
                    ((size_t)(bn + (wid << 3) + (lane >> 3)) * K) * 2 + swzc;
  const size_t s64 = (size_t)K * 128;
  const char* Lb = (const char*)L;

  {  // prologue
    unsigned short* dA = L + wid * 512;
    unsigned short* dB1 = L + 32768 + wid * 512;
    unsigned short* dB3 = L + 49152 + wid * 512;
#pragma unroll
    for (int i = 0; i < 4; ++i) GLOAD_LDS16(pA + i * s64, dA + i * 4096);
#pragma unroll
    for (int i = 0; i < 2; ++i) {
      GLOAD_LDS16(pB1 + i * s64, dB1 + i * 4096);
      GLOAD_LDS16(pB3 + i * s64, dB3 + i * 4096);
    }
  }
  pA += 128;
  pB1 += 128;
  pB3 += 128;

  f32x16 accG[2][2], accL[2][2];
#pragma unroll
  for (int m = 0; m < 2; ++m)
#pragma unroll
    for (int n = 0; n < 2; ++n) {
      accG[m][n] = (f32x16)0.0f;
      accL[m][n] = (f32x16)0.0f;
    }
  bf16x8 ra[2][4], rb1[2][4], rb3[2][4];

  VMCNT0();
  BAR();

  for (int t = 0; t < NT; t += 2) {
    G1T(0, t)
    G1T(1, t + 1)
  }

#pragma unroll
  for (int mi = 0; mi < 2; ++mi)
#pragma unroll
    for (int ni = 0; ni < 2; ++ni)
#pragma unroll
      for (int e = 0; e < 16; ++e) {
        float g = accG[mi][ni][e];
        float li = accL[mi][ni][e];
        float h = (g / (1.0f + __expf(-g))) * li;
        size_t row = (size_t)(bm + wr * 64 + mi * 32 + (e & 3) +
                              ((e >> 2) << 3) + (kk << 2));
        size_t col = (size_t)(bn + wc * 64 + ni * 32 + rl);
        Hout[row * N + col] = f32_to_bf16(h);
      }
}

extern "C" void kernel_launch(void* const* d_in, const int* in_sizes, int n_in,
                              void* d_out, int out_size, void* d_ws,
                              size_t ws_size, hipStream_t stream) {
  const float* x = (const float*)d_in[0];   // (4,2048,2048)
  const float* W1 = (const float*)d_in[1];  // (8192,2048)
  const float* W2 = (const float*)d_in[2];  // (2048,8192)
  const float* W3 = (const float*)d_in[3];  // (8192,2048)
  float* out = (float*)d_out;

  const int M = 8192, D = 2048, H = 8192;
  const size_t NE = (size_t)16777216;

  unsigned short* xb = (unsigned short*)d_ws;
  unsigned short* w1b = xb + NE;
  unsigned short* w3b = w1b + NE;
  unsigned short* w2f = w3b + NE;
  unsigned short* hid = w2f + NE;  // M x H bf16

  conv_f32_bf16<<<2048, 256, 0, stream>>>(x, xb, (int)(NE / 4));
  conv_f32_bf16<<<2048, 256, 0, stream>>>(W1, w1b, (int)(NE / 4));
  conv_f32_bf16<<<2048, 256, 0, stream>>>(W3, w3b, (int)(NE / 4));
  fwht_rows_bf16<<<2048, 256, 0, stream>>>(W2, w2f);

  gemm1_32<<<(M / 256) * (H / 128), 512, 0, stream>>>(xb, w1b, w3b, hid, M, H,
                                                      D);
  gemm2_32<<<(M / 256) * (D / 256), 512, 0, stream>>>(hid, w2f, out, M, D, H);
}

// Round 6
// 811.511 us; speedup vs baseline: 1.5369x; 1.5369x over previous
//
#include <hip/hip_runtime.h>

typedef __attribute__((ext_vector_type(8))) __bf16 bf16x8;
typedef __attribute__((ext_vector_type(4))) float f32x4;

#define GLOAD_LDS16(g, l)                                                     \
  __builtin_amdgcn_global_load_lds(                                           \
      (const __attribute__((address_space(1))) void*)(g),                     \
      (__attribute__((address_space(3))) void*)(l), 16, 0, 0)

#define BAR() __builtin_amdgcn_s_barrier()
#define SB0() __builtin_amdgcn_sched_barrier(0)
#define LGKM(n)                                                               \
  do {                                                                        \
    asm volatile("s_waitcnt lgkmcnt(" #n ")" ::: "memory");                   \
    SB0();                                                                    \
  } while (0)
#define VMCNT0() asm volatile("s_waitcnt vmcnt(0)" ::: "memory")
#define PRIO1() __builtin_amdgcn_s_setprio(1)
#define PRIO0() __builtin_amdgcn_s_setprio(0)
#define MFMA_BF16 __builtin_amdgcn_mfma_f32_16x16x32_bf16

__device__ __forceinline__ unsigned short f32_to_bf16(float f) {
  unsigned int u = __builtin_bit_cast(unsigned int, f);
  u += 0x7FFFu + ((u >> 16) & 1u);
  return (unsigned short)(u >> 16);
}

// ---------------- f32 -> bf16 conversion ----------------------------------
__global__ void conv_f32_bf16(const float* __restrict__ in,
                              unsigned short* __restrict__ out, int n4) {
  int stride = gridDim.x * blockDim.x;
  for (int i = blockIdx.x * blockDim.x + threadIdx.x; i < n4; i += stride) {
    float4 v = reinterpret_cast<const float4*>(in)[i];
    ushort4 o;
    o.x = f32_to_bf16(v.x);
    o.y = f32_to_bf16(v.y);
    o.z = f32_to_bf16(v.z);
    o.w = f32_to_bf16(v.w);
    reinterpret_cast<ushort4*>(out)[i] = o;
  }
}

// ---------------- FWHT rows of 8192, * 1/sqrt(8192), bf16 out --------------
__global__ void fwht_rows_bf16(const float* __restrict__ in,
                               unsigned short* __restrict__ out) {
  __shared__ float s[8192];
  const int tid = threadIdx.x;  // 256 threads
  const float* row = in + (size_t)blockIdx.x * 8192;
#pragma unroll
  for (int i = 0; i < 8; ++i)
    reinterpret_cast<float4*>(s)[tid + i * 256] =
        reinterpret_cast<const float4*>(row)[tid + i * 256];
  for (int h = 1; h < 8192; h <<= 1) {
    __syncthreads();
#pragma unroll
    for (int it = 0; it < 16; ++it) {
      int i = tid + it * 256;
      int j = ((i & ~(h - 1)) << 1) | (i & (h - 1));
      float a = s[j], b = s[j + h];
      s[j] = a + b;
      s[j + h] = a - b;
    }
  }
  __syncthreads();
  const float scale = 0.011048543456039806f;  // 1/sqrt(8192)
  unsigned short* orow = out + (size_t)blockIdx.x * 8192;
#pragma unroll
  for (int i = 0; i < 8; ++i) {
    float4 v = reinterpret_cast<const float4*>(s)[tid + i * 256];
    ushort4 o;
    o.x = f32_to_bf16(v.x * scale);
    o.y = f32_to_bf16(v.y * scale);
    o.z = f32_to_bf16(v.z * scale);
    o.w = f32_to_bf16(v.w * scale);
    reinterpret_cast<ushort4*>(orow)[tid + i * 256] = o;
  }
}

// ======================= GEMM2: C(f32) = A · Bt^T ==========================
// tile 256x256, BK=64, 8 waves (2M x 4N), per-wave 128x64.
// One barrier + one vmcnt(0) per K-tile; STAGE ISSUED FIRST (tile head) so
// the global_load_lds supply hides under the full ds_read+MFMA phase.
#define G2_TILE(BI, tt)                                                       \
  {                                                                           \
    if ((tt) + 1 < NT) {                                                      \
      unsigned short* dA = L + (((BI) ^ 1) * 16384) + wid * 512;              \
      unsigned short* dB = L + 32768 + (((BI) ^ 1) * 16384) + wid * 512;      \
      _Pragma("unroll") for (int i = 0; i < 4; ++i) {                         \
        GLOAD_LDS16(pA + i * s64, dA + i * 4096);                             \
        GLOAD_LDS16(pB + i * s64, dB + i * 4096);                             \
      }                                                                       \
    }                                                                         \
    SB0();                                                                    \
    _Pragma("unroll") for (int m = 0; m < 4; ++m) {                           \
      ra[m][0] = *(const bf16x8*)(Lb + ((BI)*32768 + m * 2048) + rA0);        \
      ra[m][1] = *(const bf16x8*)(Lb + ((BI)*32768 + m * 2048) + rA1);        \
    }                                                                         \
    _Pragma("unroll") for (int n = 0; n < 2; ++n) {                           \
      rb[n][0] = *(const bf16x8*)(Lb + ((BI)*32768 + n * 2048) + rB0);        \
      rb[n][1] = *(const bf16x8*)(Lb + ((BI)*32768 + n * 2048) + rB1);        \
    }                                                                         \
    SB0();                                                                    \
    _Pragma("unroll") for (int n = 2; n < 4; ++n) {                           \
      rb[n][0] = *(const bf16x8*)(Lb + ((BI)*32768 + n * 2048) + rB0);        \
      rb[n][1] = *(const bf16x8*)(Lb + ((BI)*32768 + n * 2048) + rB1);        \
    }                                                                         \
    SB0();                                                                    \
    LGKM(4);                                                                  \
    PRIO1();                                                                  \
    _Pragma("unroll") for (int m = 0; m < 4; ++m)                             \
        _Pragma("unroll") for (int n = 0; n < 2; ++n) {                       \
      acc[m][n] = MFMA_BF16(ra[m][0], rb[n][0], acc[m][n], 0, 0, 0);          \
      acc[m][n] = MFMA_BF16(ra[m][1], rb[n][1], acc[m][n], 0, 0, 0);          \
    }                                                                         \
    PRIO0();                                                                  \
    SB0();                                                                    \
    LGKM(0);                                                                  \
    PRIO1();                                                                  \
    _Pragma("unroll") for (int m = 0; m < 4; ++m)                             \
        _Pragma("unroll") for (int n = 2; n < 4; ++n) {                       \
      acc[m][n] = MFMA_BF16(ra[m][0], rb[n][0], acc[m][n], 0, 0, 0);          \
      acc[m][n] = MFMA_BF16(ra[m][1], rb[n][1], acc[m][n], 0, 0, 0);          \
    }                                                                         \
    PRIO0();                                                                  \
    SB0();                                                                    \
    _Pragma("unroll") for (int m = 0; m < 4; ++m) {                           \
      ra[m][0] = *(const bf16x8*)(Lb + ((BI)*32768 + (m + 4) * 2048) + rA0);  \
      ra[m][1] = *(const bf16x8*)(Lb + ((BI)*32768 + (m + 4) * 2048) + rA1);  \
    }                                                                         \
    SB0();                                                                    \
    LGKM(0);                                                                  \
    PRIO1();                                                                  \
    _Pragma("unroll") for (int m = 0; m < 4; ++m)                             \
        _Pragma("unroll") for (int n = 2; n < 4; ++n) {                       \
      acc[4 + m][n] = MFMA_BF16(ra[m][0], rb[n][0], acc[4 + m][n], 0, 0, 0);  \
      acc[4 + m][n] = MFMA_BF16(ra[m][1], rb[n][1], acc[4 + m][n], 0, 0, 0);  \
    }                                                                         \
    _Pragma("unroll") for (int m = 0; m < 4; ++m)                             \
        _Pragma("unroll") for (int n = 0; n < 2; ++n) {                       \
      acc[4 + m][n] = MFMA_BF16(ra[m][0], rb[n][0], acc[4 + m][n], 0, 0, 0);  \
      acc[4 + m][n] = MFMA_BF16(ra[m][1], rb[n][1], acc[4 + m][n], 0, 0, 0);  \
    }                                                                         \
    PRIO0();                                                                  \
    VMCNT0();                                                                 \
    BAR();                                                                    \
    pA += 128;                                                                \
    pB += 128;                                                                \
  }

__launch_bounds__(512, 2)
__global__ void gemm2_pipe(const unsigned short* __restrict__ A,
                           const unsigned short* __restrict__ Bt,
                           float* __restrict__ C, int M, int N, int K) {
  __shared__ __align__(16) unsigned short L[65536];  // A:[0,64KB) B:[64,128KB)
  const int tid = threadIdx.x, lane = tid & 63, wid = tid >> 6;
  const int wr = wid >> 2, wc = wid & 3;
  const int nbx = N >> 8;
  const int cpx = (int)gridDim.x >> 3;
  const int swz = ((int)blockIdx.x & 7) * cpx + ((int)blockIdx.x >> 3);
  const int bm = (swz / nbx) << 8, bn = (swz % nbx) << 8;
  const int NT = K >> 6;

  // per-lane LDS read offsets (swizzle folded): ks=0 / ks=1
  const int lp0 = (lane & 15) * 128 + (((lane >> 4) << 4) ^ ((lane & 7) << 4));
  const int lp1 =
      (lane & 15) * 128 + ((64 | ((lane >> 4) << 4)) ^ ((lane & 7) << 4));
  const int rA0 = wr * 16384 + lp0, rA1 = wr * 16384 + lp1;
  const int rB0 = 65536 + wc * 8192 + lp0, rB1 = 65536 + wc * 8192 + lp1;

  // per-lane global stage pointers (inverse swizzle folded into source col)
  const int swzc = ((lane & 7) ^ (lane >> 3)) << 4;
  const char* pA = (const char*)A +
                   ((size_t)(bm + (wid << 3) + (lane >> 3)) * K) * 2 + swzc;
  const char* pB = (const char*)Bt +
                   ((size_t)(bn + (wid << 3) + (lane >> 3)) * K) * 2 + swzc;
  const size_t s64 = (size_t)K * 128;  // 64 rows stride (bytes)
  const char* Lb = (const char*)L;

  {  // prologue: stage tile 0 into buf0
    unsigned short* dA = L + wid * 512;
    unsigned short* dB = L + 32768 + wid * 512;
#pragma unroll
    for (int i = 0; i < 4; ++i) {
      GLOAD_LDS16(pA + i * s64, dA + i * 4096);
      GLOAD_LDS16(pB + i * s64, dB + i * 4096);
    }
  }
  pA += 128;
  pB += 128;

  f32x4 acc[8][4];
#pragma unroll
  for (int m = 0; m < 8; ++m)
#pragma unroll
    for (int n = 0; n < 4; ++n) acc[m][n] = (f32x4)0.0f;
  bf16x8 ra[4][2], rb[4][2];

  VMCNT0();
  BAR();

  for (int t = 0; t < NT; t += 2) {
    G2_TILE(0, t)
    G2_TILE(1, t + 1)
  }

  const int er = (lane >> 4) << 2;
  const int ec = lane & 15;
#pragma unroll
  for (int mi = 0; mi < 8; ++mi)
#pragma unroll
    for (int n = 0; n < 4; ++n)
#pragma unroll
      for (int r = 0; r < 4; ++r) {
        size_t row = (size_t)(bm + wr * 128 + mi * 16 + er + r);
        size_t col = (size_t)(bn + wc * 64 + n * 16 + ec);
        C[row * N + col] = acc[mi][n][r];
      }
}

// ======================= GEMM1: dual-B + silu fuse =========================
// tile 256x128, BK=64, 8 waves (4M x 2N), per-wave 64x64, dual accum.
// LDS carve (ushorts): A [0,32768), B1 [32768,49152), B3 [49152,65536).
// STAGE ISSUED FIRST (tile head); 1 barrier + 1 vmcnt(0) per K-tile.
#define G1_TILE(BI, tt)                                                       \
  {                                                                           \
    if ((tt) + 1 < NT) {                                                      \
      unsigned short* dA = L + (((BI) ^ 1) * 16384) + wid * 512;              \
      unsigned short* dB1 = L + 32768 + (((BI) ^ 1) * 8192) + wid * 512;      \
      unsigned short* dB3 = L + 49152 + (((BI) ^ 1) * 8192) + wid * 512;      \
      _Pragma("unroll") for (int i = 0; i < 4; ++i)                           \
          GLOAD_LDS16(pA + i * s64, dA + i * 4096);                           \
      _Pragma("unroll") for (int i = 0; i < 2; ++i) {                         \
        GLOAD_LDS16(pB1 + i * s64, dB1 + i * 4096);                           \
        GLOAD_LDS16(pB3 + i * s64, dB3 + i * 4096);                           \
      }                                                                       \
    }                                                                         \
    SB0();                                                                    \
    _Pragma("unroll") for (int m = 0; m < 4; ++m) {                           \
      ra[m][0] = *(const bf16x8*)(Lb + ((BI)*32768 + m * 2048) + rA0);        \
      ra[m][1] = *(const bf16x8*)(Lb + ((BI)*32768 + m * 2048) + rA1);        \
    }                                                                         \
    _Pragma("unroll") for (int n = 0; n < 2; ++n) {                           \
      rb[n][0] = *(const bf16x8*)(Lb + ((BI)*16384 + n * 2048) + rB0);        \
      rb[n][1] = *(const bf16x8*)(Lb + ((BI)*16384 + n * 2048) + rB1);        \
    }                                                                         \
    SB0();                                                                    \
    _Pragma("unroll") for (int n = 2; n < 4; ++n) {                           \
      rb[n][0] = *(const bf16x8*)(Lb + ((BI)*16384 + n * 2048) + rB0);        \
      rb[n][1] = *(const bf16x8*)(Lb + ((BI)*16384 + n * 2048) + rB1);        \
    }                                                                         \
    SB0();                                                                    \
    LGKM(4);                                                                  \
    PRIO1();                                                                  \
    _Pragma("unroll") for (int m = 0; m < 4; ++m)                             \
        _Pragma("unroll") for (int n = 0; n < 2; ++n) {                       \
      accG[m][n] = MFMA_BF16(ra[m][0], rb[n][0], accG[m][n], 0, 0, 0);        \
      accG[m][n] = MFMA_BF16(ra[m][1], rb[n][1], accG[m][n], 0, 0, 0);        \
    }                                                                         \
    PRIO0();                                                                  \
    SB0();                                                                    \
    LGKM(0);                                                                  \
    PRIO1();                                                                  \
    _Pragma("unroll") for (int m = 0; m < 4; ++m)                             \
        _Pragma("unroll") for (int n = 2; n < 4; ++n) {                       \
      accG[m][n] = MFMA_BF16(ra[m][0], rb[n][0], accG[m][n], 0, 0, 0);        \
      accG[m][n] = MFMA_BF16(ra[m][1], rb[n][1], accG[m][n], 0, 0, 0);        \
    }                                                                         \
    PRIO0();                                                                  \
    SB0();                                                                    \
    _Pragma("unroll") for (int n = 2; n < 4; ++n) { /* B3 n2,3 first */       \
      rb[n][0] = *(const bf16x8*)(Lb + (32768 + (BI)*16384 + n * 2048) + rB0);\
      rb[n][1] = *(const bf16x8*)(Lb + (32768 + (BI)*16384 + n * 2048) + rB1);\
    }                                                                         \
    SB0();                                                                    \
    _Pragma("unroll") for (int n = 0; n < 2; ++n) {                           \
      rb[n][0] = *(const bf16x8*)(Lb + (32768 + (BI)*16384 + n * 2048) + rB0);\
      rb[n][1] = *(const bf16x8*)(Lb + (32768 + (BI)*16384 + n * 2048) + rB1);\
    }                                                                         \
    SB0();                                                                    \
    LGKM(4);                                                                  \
    PRIO1();                                                                  \
    _Pragma("unroll") for (int m = 0; m < 4; ++m)                             \
        _Pragma("unroll") for (int n = 2; n < 4; ++n) {                       \
      accL[m][n] = MFMA_BF16(ra[m][0], rb[n][0], accL[m][n], 0, 0, 0);        \
      accL[m][n] = MFMA_BF16(ra[m][1], rb[n][1], accL[m][n], 0, 0, 0);        \
    }                                                                         \
    PRIO0();                                                                  \
    SB0();                                                                    \
    LGKM(0);                                                                  \
    PRIO1();                                                                  \
    _Pragma("unroll") for (int m = 0; m < 4; ++m)                             \
        _Pragma("unroll") for (int n = 0; n < 2; ++n) {                       \
      accL[m][n] = MFMA_BF16(ra[m][0], rb[n][0], accL[m][n], 0, 0, 0);        \
      accL[m][n] = MFMA_BF16(ra[m][1], rb[n][1], accL[m][n], 0, 0, 0);        \
    }                                                                         \
    PRIO0();                                                                  \
    VMCNT0();                                                                 \
    BAR();                                                                    \
    pA += 128;                                                                \
    pB1 += 128;                                                               \
    pB3 += 128;                                                               \
  }

__launch_bounds__(512, 2)
__global__ void gemm1_pipe(const unsigned short* __restrict__ A,
                           const unsigned short* __restrict__ B1p,
                           const unsigned short* __restrict__ B3p,
                           unsigned short* __restrict__ Hout, int M, int N,
                           int K) {
  __shared__ __align__(16) unsigned short L[65536];
  const int tid = threadIdx.x, lane = tid & 63, wid = tid >> 6;
  const int wr = wid >> 1, wc = wid & 1;
  const int nby = M >> 8;  // 32
  const int cpx = (int)gridDim.x >> 3;
  const int swz = ((int)blockIdx.x & 7) * cpx + ((int)blockIdx.x >> 3);
  const int bm = (swz % nby) << 8;
  const int bn = (swz / nby) << 7;
  const int NT = K >> 6;

  const int lp0 = (lane & 15) * 128 + (((lane >> 4) << 4) ^ ((lane & 7) << 4));
  const int lp1 =
      (lane & 15) * 128 + ((64 | ((lane >> 4) << 4)) ^ ((lane & 7) << 4));
  const int rA0 = wr * 8192 + lp0, rA1 = wr * 8192 + lp1;
  const int rB0 = 65536 + wc * 8192 + lp0, rB1 = 65536 + wc * 8192 + lp1;

  const int swzc = ((lane & 7) ^ (lane >> 3)) << 4;
  const char* pA = (const char*)A +
                   ((size_t)(bm + (wid << 3) + (lane >> 3)) * K) * 2 + swzc;
  const char* pB1 = (const char*)B1p +
                    ((size_t)(bn + (wid << 3) + (lane >> 3)) * K) * 2 + swzc;
  const char* pB3 = (const char*)B3p +
                    ((size_t)(bn + (wid << 3) + (lane >> 3)) * K) * 2 + swzc;
  const size_t s64 = (size_t)K * 128;
  const char* Lb = (const char*)L;

  {  // prologue
    unsigned short* dA = L + wid * 512;
    unsigned short* dB1 = L + 32768 + wid * 512;
    unsigned short* dB3 = L + 49152 + wid * 512;
#pragma unroll
    for (int i = 0; i < 4; ++i) GLOAD_LDS16(pA + i * s64, dA + i * 4096);
#pragma unroll
    for (int i = 0; i < 2; ++i) {
      GLOAD_LDS16(pB1 + i * s64, dB1 + i * 4096);
      GLOAD_LDS16(pB3 + i * s64, dB3 + i * 4096);
    }
  }
  pA += 128;
  pB1 += 128;
  pB3 += 128;

  f32x4 accG[4][4], accL[4][4];
#pragma unroll
  for (int m = 0; m < 4; ++m)
#pragma unroll
    for (int n = 0; n < 4; ++n) {
      accG[m][n] = (f32x4)0.0f;
      accL[m][n] = (f32x4)0.0f;
    }
  bf16x8 ra[4][2], rb[4][2];

  VMCNT0();
  BAR();

  for (int t = 0; t < NT; t += 2) {
    G1_TILE(0, t)
    G1_TILE(1, t + 1)
  }

  const int er = (lane >> 4) << 2;
  const int ec = lane & 15;
#pragma unroll
  for (int m = 0; m < 4; ++m)
#pragma unroll
    for (int n = 0; n < 4; ++n)
#pragma unroll
      for (int r = 0; r < 4; ++r) {
        float g = accG[m][n][r];
        float li = accL[m][n][r];
        float h = (g / (1.0f + __expf(-g))) * li;
        size_t row = (size_t)(bm + wr * 64 + m * 16 + er + r);
        size_t col = (size_t)(bn + wc * 64 + n * 16 + ec);
        Hout[row * N + col] = f32_to_bf16(h);
      }
}

extern "C" void kernel_launch(void* const* d_in, const int* in_sizes, int n_in,
                              void* d_out, int out_size, void* d_ws,
                              size_t ws_size, hipStream_t stream) {
  const float* x = (const float*)d_in[0];   // (4,2048,2048)
  const float* W1 = (const float*)d_in[1];  // (8192,2048)
  const float* W2 = (const float*)d_in[2];  // (2048,8192)
  const float* W3 = (const float*)d_in[3];  // (8192,2048)
  float* out = (float*)d_out;

  const int M = 8192, D = 2048, H = 8192;
  const size_t NE = (size_t)16777216;

  unsigned short* xb = (unsigned short*)d_ws;
  unsigned short* w1b = xb + NE;
  unsigned short* w3b = w1b + NE;
  unsigned short* w2f = w3b + NE;
  unsigned short* hid = w2f + NE;  // M x H bf16

  conv_f32_bf16<<<2048, 256, 0, stream>>>(x, xb, (int)(NE / 4));
  conv_f32_bf16<<<2048, 256, 0, stream>>>(W1, w1b, (int)(NE / 4));
  conv_f32_bf16<<<2048, 256, 0, stream>>>(W3, w3b, (int)(NE / 4));
  fwht_rows_bf16<<<2048, 256, 0, stream>>>(W2, w2f);

  gemm1_pipe<<<(M / 256) * (H / 128), 512, 0, stream>>>(xb, w1b, w3b, hid, M,
                                                        H, D);
  gemm2_pipe<<<(M / 256) * (D / 256), 512, 0, stream>>>(hid, w2f, out, M, D,
                                                        H);
}